// Round 8
// baseline (844.059 us; speedup 1.0000x reference)
//
#include <hip/hip_runtime.h>
#include <hip/hip_fp16.h>
#include <hip/hip_cooperative_groups.h>

namespace cg = cooperative_groups;

#define NEG 0.2f
#define BSHIFT 9
#define BNODES 512          // dst nodes per bucket
#define ECAP 14336          // fixed region per bucket (mean ~12288, sd ~110 -> +18 sigma)

typedef _Float16 half8_t __attribute__((ext_vector_type(8)));
typedef float   floatx4_t __attribute__((ext_vector_type(4)));
typedef float   floatx2_t __attribute__((ext_vector_type(2)));

struct MegaP {
    const int *src, *dst;
    int *gcur; unsigned *binned;
    int E, K, N, EB, GB, AB;
    const float *W1s, *a1s, *W1d, *a1d, *W2s, *a2s, *W2d, *a2d, *Wl1, *Wl2;
    __half *wf;
    int *ssrc, *rowbeg, *rowend;
    const float *x;
    const float *b1, *bl1, *b2, *bl2;
    unsigned *hsrc8_1; float *base1, *asrc1, *adst1;
    unsigned *hsrc8_2; float *base2, *asrc2, *adst2;
    float *out;
};

// ---------------------------------------------------------------------------
// Aggregation core: one dst node per 16-lane group (4 nodes/wave).
// Lane l owns channels 4l..4l+3. No shuffles, no reduction (sumw replicated).
// ---------------------------------------------------------------------------
__device__ __forceinline__ void agg16(
    int beg, int end, float ad, int l,
    const int* __restrict__ ssrc, const float* __restrict__ asrc,
    const unsigned* __restrict__ h4,
    float& a0, float& a1, float& a2, float& a3, float& sumw) {
    a0 = a1 = a2 = a3 = sumw = 0.f;
    int e = beg;
    for (; e + 3 < end; e += 4) {
        int s0 = ssrc[e], s1 = ssrc[e + 1], s2 = ssrc[e + 2], s3 = ssrc[e + 3];
        float x0 = asrc[s0] + ad, x1 = asrc[s1] + ad;
        float x2 = asrc[s2] + ad, x3 = asrc[s3] + ad;
        unsigned v0 = h4[(size_t)s0 * 16 + l];
        unsigned v1 = h4[(size_t)s1 * 16 + l];
        unsigned v2 = h4[(size_t)s2 * 16 + l];
        unsigned v3 = h4[(size_t)s3 * 16 + l];
        x0 = (x0 >= 0.f) ? x0 : NEG * x0;
        x1 = (x1 >= 0.f) ? x1 : NEG * x1;
        x2 = (x2 >= 0.f) ? x2 : NEG * x2;
        x3 = (x3 >= 0.f) ? x3 : NEG * x3;
        float w0 = __expf(x0), w1 = __expf(x1), w2 = __expf(x2), w3 = __expf(x3);
        floatx2_t f00 = __builtin_amdgcn_cvt_pk_f32_fp8(v0, false);
        floatx2_t f01 = __builtin_amdgcn_cvt_pk_f32_fp8(v0, true);
        floatx2_t f10 = __builtin_amdgcn_cvt_pk_f32_fp8(v1, false);
        floatx2_t f11 = __builtin_amdgcn_cvt_pk_f32_fp8(v1, true);
        floatx2_t f20 = __builtin_amdgcn_cvt_pk_f32_fp8(v2, false);
        floatx2_t f21 = __builtin_amdgcn_cvt_pk_f32_fp8(v2, true);
        floatx2_t f30 = __builtin_amdgcn_cvt_pk_f32_fp8(v3, false);
        floatx2_t f31 = __builtin_amdgcn_cvt_pk_f32_fp8(v3, true);
        sumw += (w0 + w1) + (w2 + w3);
        a0 += w0 * f00.x + w1 * f10.x + w2 * f20.x + w3 * f30.x;
        a1 += w0 * f00.y + w1 * f10.y + w2 * f20.y + w3 * f30.y;
        a2 += w0 * f01.x + w1 * f11.x + w2 * f21.x + w3 * f31.x;
        a3 += w0 * f01.y + w1 * f11.y + w2 * f21.y + w3 * f31.y;
    }
    for (; e < end; ++e) {
        int s = ssrc[e];
        float x = asrc[s] + ad;
        unsigned v = h4[(size_t)s * 16 + l];
        x = (x >= 0.f) ? x : NEG * x;
        float w = __expf(x);
        floatx2_t f0 = __builtin_amdgcn_cvt_pk_f32_fp8(v, false);
        floatx2_t f1 = __builtin_amdgcn_cvt_pk_f32_fp8(v, true);
        sumw += w;
        a0 += w * f0.x; a1 += w * f0.y;
        a2 += w * f1.x; a3 += w * f1.y;
    }
}

// ---------------------------------------------------------------------------
// MFMA GEMM tile: 64 rows fp16 in xh[64][72]. Wave w owns rows 16w..16w+15.
// 18 MFMAs; epilogue LDS-bounces: hsrc -> fp8 (packed), base -> fp32 (+bias),
// asrc/adst from the attention MFMA's C-frag columns 0/1.
// ---------------------------------------------------------------------------
__device__ __forceinline__ void mfma_tile(
    int tid, int row0, int rows,
    _Float16* xh, float* xf,            // aliased LDS (union), used sequentially
    const __half* wsF, const __half* wlF, const __half* wvF,
    const float* __restrict__ bconv, const float* __restrict__ blin,
    unsigned* __restrict__ hsrc8, float* __restrict__ base_out,
    float* __restrict__ asrc, float* __restrict__ adst) {
    int w = tid >> 6, lane = tid & 63, m = lane & 15, q = lane >> 4;
    half8_t a0 = *(const half8_t*)&xh[(w * 16 + m) * 72 + q * 8];
    half8_t a1 = *(const half8_t*)&xh[(w * 16 + m) * 72 + 32 + q * 8];
    const half8_t* bS = (const half8_t*)(const void*)wsF;
    const half8_t* bL = (const half8_t*)(const void*)wlF;
    const half8_t* bV = (const half8_t*)(const void*)wvF;
    floatx4_t z = {0.f, 0.f, 0.f, 0.f};
    floatx4_t cs[4], cl[4], cv;
    #pragma unroll
    for (int nt = 0; nt < 4; ++nt) {
        cs[nt] = __builtin_amdgcn_mfma_f32_16x16x32_f16(a0, bS[(nt * 2 + 0) * 64 + lane], z, 0, 0, 0);
        cs[nt] = __builtin_amdgcn_mfma_f32_16x16x32_f16(a1, bS[(nt * 2 + 1) * 64 + lane], cs[nt], 0, 0, 0);
        cl[nt] = __builtin_amdgcn_mfma_f32_16x16x32_f16(a0, bL[(nt * 2 + 0) * 64 + lane], z, 0, 0, 0);
        cl[nt] = __builtin_amdgcn_mfma_f32_16x16x32_f16(a1, bL[(nt * 2 + 1) * 64 + lane], cl[nt], 0, 0, 0);
    }
    cv = __builtin_amdgcn_mfma_f32_16x16x32_f16(a0, bV[lane], z, 0, 0, 0);
    cv = __builtin_amdgcn_mfma_f32_16x16x32_f16(a1, bV[64 + lane], cv, 0, 0, 0);
    __syncthreads();
    #pragma unroll
    for (int nt = 0; nt < 4; ++nt)
        #pragma unroll
        for (int r = 0; r < 4; ++r)
            xf[(w * 16 + q * 4 + r) * 68 + nt * 16 + m] = cs[nt][r];
    __syncthreads();
    #pragma unroll
    for (int i = 0; i < 2; ++i) {
        int u = tid + i * 256;
        int r = u >> 3, c8 = (u & 7) * 8;
        if (r < rows) {
            float4 v0 = *(const float4*)&xf[r * 68 + c8];
            float4 v1 = *(const float4*)&xf[r * 68 + c8 + 4];
            int lo = __builtin_amdgcn_cvt_pk_fp8_f32(v0.x, v0.y, 0, false);
            lo = __builtin_amdgcn_cvt_pk_fp8_f32(v0.z, v0.w, lo, true);
            int hi = __builtin_amdgcn_cvt_pk_fp8_f32(v1.x, v1.y, 0, false);
            hi = __builtin_amdgcn_cvt_pk_fp8_f32(v1.z, v1.w, hi, true);
            uint2 pk; pk.x = (unsigned)lo; pk.y = (unsigned)hi;
            *(uint2*)&hsrc8[(size_t)(row0 + r) * 16 + (u & 7) * 2] = pk;
        }
    }
    __syncthreads();
    float bb[4];
    bb[0] = bconv[m] + blin[m];
    bb[1] = bconv[16 + m] + blin[16 + m];
    bb[2] = bconv[32 + m] + blin[32 + m];
    bb[3] = bconv[48 + m] + blin[48 + m];
    #pragma unroll
    for (int nt = 0; nt < 4; ++nt)
        #pragma unroll
        for (int r = 0; r < 4; ++r)
            xf[(w * 16 + q * 4 + r) * 68 + nt * 16 + m] = cl[nt][r] + bb[nt];
    __syncthreads();
    #pragma unroll
    for (int i = 0; i < 4; ++i) {
        int u = tid + i * 256;
        int r = u >> 4, c4 = (u & 15) * 4;
        if (r < rows)
            *(float4*)&base_out[(size_t)(row0 + r) * 64 + c4] = *(const float4*)&xf[r * 68 + c4];
    }
    int rb = w * 16 + q * 4;
    if (m == 0) {
        #pragma unroll
        for (int r = 0; r < 4; ++r)
            if (rb + r < rows) asrc[row0 + rb + r] = cv[r];
    } else if (m == 1) {
        #pragma unroll
        for (int r = 0; r < 4; ++r)
            if (rb + r < rows) adst[row0 + rb + r] = cv[r];
    }
}

// ---------------------------------------------------------------------------
// Cooperative mega kernel (grid-stride phases, any grid size >= 1).
// ---------------------------------------------------------------------------
__global__ __launch_bounds__(256, 4) void mega(MegaP p) {
    cg::grid_group grid = cg::this_grid();
    __shared__ union {
        struct { int h[128], cbase[128], cur[128]; } b;
        float vsm[256];
        struct { int lh[512]; int ps[256]; } c;
        _Float16 xh[64 * 72];
        float    xf[64 * 68];
    } sm;
    int tid = threadIdx.x;

    // ---- P0: zero bucket cursors ----
    if (blockIdx.x == 0 && tid < 128) p.gcur[tid] = 0;
    __threadfence();
    grid.sync();
    __threadfence();

    // ---- P1: weight-frag prep (block 0) + edge binning (grid-stride) ----
    if (blockIdx.x == 0) {
        {
            int g = tid >> 6, k = tid & 63;
            const float* W = (g == 0) ? p.W1s : (g == 1) ? p.W1d : (g == 2) ? p.W2s : p.W2d;
            const float* a = (g == 0) ? p.a1s : (g == 1) ? p.a1d : (g == 2) ? p.a2s : p.a2d;
            float s = 0.f;
            #pragma unroll 8
            for (int j = 0; j < 64; ++j) s += W[k * 64 + j] * a[j];
            sm.vsm[tid] = s;
        }
        __syncthreads();
        __half* wS1 = p.wf;
        __half* wL1 = p.wf + 4096;
        __half* wV1 = p.wf + 8192;
        __half* wS2 = p.wf + 9216;
        __half* wL2 = p.wf + 13312;
        __half* wV2 = p.wf + 17408;
        for (int e = tid; e < 4096; e += 256) {
            int j = e & 7, ln = (e >> 3) & 63, tile = e >> 9;
            int nt = tile >> 1, kt = tile & 1;
            int kk = kt * 32 + ((ln >> 4) << 3) + j;
            int nn = (nt << 4) + (ln & 15);
            int wi = kk * 64 + nn;
            wS1[e] = __float2half(p.W1s[wi]);
            wL1[e] = __float2half(p.Wl1[wi]);
            wS2[e] = __float2half(p.W2s[wi]);
            wL2[e] = __float2half(p.Wl2[wi]);
        }
        for (int e = tid; e < 1024; e += 256) {
            int j = e & 7, ln = (e >> 3) & 63, kt = e >> 9;
            int kk = kt * 32 + ((ln >> 4) << 3) + j;
            int nn = ln & 15;
            float v1 = (nn == 0) ? sm.vsm[kk] : (nn == 1) ? sm.vsm[64 + kk] : 0.f;
            float v2 = (nn == 0) ? sm.vsm[128 + kk] : (nn == 1) ? sm.vsm[192 + kk] : 0.f;
            wV1[e] = __float2half(v1);
            wV2[e] = __float2half(v2);
        }
        __syncthreads();
    }
    for (int u = blockIdx.x; u < p.EB; u += (int)gridDim.x) {
        if (tid < 128) sm.b.h[tid] = 0;
        __syncthreads();
        int base = u * 2048;
        #pragma unroll
        for (int i = 0; i < 8; ++i) {
            int idx = base + i * 256 + tid;
            if (idx < p.E) atomicAdd(&sm.b.h[p.dst[idx] >> BSHIFT], 1);
        }
        __syncthreads();
        if (tid < p.K) {
            sm.b.cbase[tid] = tid * ECAP +
                (sm.b.h[tid] ? atomicAdd(&p.gcur[tid], sm.b.h[tid]) : 0);
            sm.b.cur[tid] = 0;
        }
        __syncthreads();
        #pragma unroll
        for (int i = 0; i < 8; ++i) {
            int idx = base + i * 256 + tid;
            if (idx < p.E) {
                int d = p.dst[idx], s = p.src[idx];
                int b = d >> BSHIFT;
                int pos = sm.b.cbase[b] + atomicAdd(&sm.b.cur[b], 1);
                p.binned[pos] = ((unsigned)s << BSHIFT) | (unsigned)(d & (BNODES - 1));
            }
        }
        __syncthreads();
    }
    __threadfence();
    grid.sync();
    __threadfence();

    // ---- P2: per-bucket CSR finalize (u < K) + conv1 MFMA gemm ----
    for (int u = blockIdx.x; u < p.K + p.GB; u += (int)gridDim.x) {
        if (u < p.K) {
            int base = u * ECAP;
            int cnt = min(p.gcur[u], ECAP);
            sm.c.lh[tid] = 0; sm.c.lh[tid + 256] = 0;
            __syncthreads();
            for (int i = tid; i < cnt; i += 256)
                atomicAdd(&sm.c.lh[p.binned[base + i] & (BNODES - 1)], 1);
            __syncthreads();
            int a0 = sm.c.lh[2 * tid], a1 = sm.c.lh[2 * tid + 1];
            sm.c.ps[tid] = a0 + a1;
            __syncthreads();
            for (int off = 1; off < 256; off <<= 1) {
                int v = (tid >= off) ? sm.c.ps[tid - off] : 0;
                __syncthreads();
                sm.c.ps[tid] += v;
                __syncthreads();
            }
            int exc = sm.c.ps[tid] - (a0 + a1);
            int node0 = u * BNODES + 2 * tid, node1 = node0 + 1;
            if (node0 < p.N) { p.rowbeg[node0] = base + exc;      p.rowend[node0] = base + exc + a0; }
            if (node1 < p.N) { p.rowbeg[node1] = base + exc + a0; p.rowend[node1] = base + exc + a0 + a1; }
            __syncthreads();
            sm.c.lh[2 * tid] = exc; sm.c.lh[2 * tid + 1] = exc + a0;
            __syncthreads();
            for (int i = tid; i < cnt; i += 256) {
                unsigned e = p.binned[base + i];
                int pos = atomicAdd(&sm.c.lh[e & (BNODES - 1)], 1);
                p.ssrc[base + pos] = (int)(e >> BSHIFT);
            }
        } else {
            int row0 = (u - p.K) * 64;
            int rows = min(64, p.N - row0);
            #pragma unroll
            for (int i = 0; i < 4; ++i) {
                int uu = tid + i * 256;
                int r = uu >> 4, c4 = (uu & 15) * 4;
                if (r < rows) {
                    float4 v = *(const float4*)&p.x[(size_t)(row0 + r) * 64 + c4];
                    *(__half2*)&sm.xh[r * 72 + c4]     = __floats2half2_rn(v.x, v.y);
                    *(__half2*)&sm.xh[r * 72 + c4 + 2] = __floats2half2_rn(v.z, v.w);
                }
            }
            __syncthreads();
            mfma_tile(tid, row0, rows, sm.xh, sm.xf,
                      p.wf, p.wf + 4096, p.wf + 8192,
                      p.b1, p.bl1, p.hsrc8_1, p.base1, p.asrc1, p.adst1);
        }
        __syncthreads();
    }
    __threadfence();
    grid.sync();
    __threadfence();

    // ---- P3: conv1 aggregate into LDS tile + conv2 MFMA gemm ----
    for (int u = blockIdx.x; u < p.GB; u += (int)gridDim.x) {
        int row0 = u * 64;
        int rows = min(64, p.N - row0);
        int g = tid >> 4, l = tid & 15;
        #pragma unroll
        for (int r = 0; r < 4; ++r) {
            int rl = r * 16 + g;
            int d = row0 + rl;
            if (rl < rows) {
                float a0, a1, a2, a3, sw;
                agg16(p.rowbeg[d], p.rowend[d], p.adst1[d], l,
                      p.ssrc, p.asrc1, p.hsrc8_1, a0, a1, a2, a3, sw);
                float4 b4 = *(const float4*)&p.base1[(size_t)d * 64 + 4 * l];
                float invw = (sw > 0.f) ? 1.f / sw : 0.f;
                __half2 p0 = __floats2half2_rn(fmaxf(b4.x + a0 * invw, 0.f),
                                               fmaxf(b4.y + a1 * invw, 0.f));
                __half2 p1 = __floats2half2_rn(fmaxf(b4.z + a2 * invw, 0.f),
                                               fmaxf(b4.w + a3 * invw, 0.f));
                *(__half2*)&sm.xh[rl * 72 + 4 * l]     = p0;
                *(__half2*)&sm.xh[rl * 72 + 4 * l + 2] = p1;
            }
        }
        __syncthreads();
        mfma_tile(tid, row0, rows, sm.xh, sm.xf,
                  p.wf + 9216, p.wf + 13312, p.wf + 17408,
                  p.b2, p.bl2, p.hsrc8_2, p.base2, p.asrc2, p.adst2);
        __syncthreads();
    }
    __threadfence();
    grid.sync();
    __threadfence();

    // ---- P4: conv2 aggregate -> fp32 output ----
    for (int u = blockIdx.x; u < p.AB; u += (int)gridDim.x) {
        int d = u * 16 + (tid >> 4);
        int l = tid & 15;
        if (d < p.N) {
            float a0, a1, a2, a3, sw;
            agg16(p.rowbeg[d], p.rowend[d], p.adst2[d], l,
                  p.ssrc, p.asrc2, p.hsrc8_2, a0, a1, a2, a3, sw);
            float4 b4 = *(const float4*)&p.base2[(size_t)d * 64 + 4 * l];
            float invw = (sw > 0.f) ? 1.f / sw : 0.f;
            float4 o;
            o.x = fmaxf(b4.x + a0 * invw, 0.f);
            o.y = fmaxf(b4.y + a1 * invw, 0.f);
            o.z = fmaxf(b4.z + a2 * invw, 0.f);
            o.w = fmaxf(b4.w + a3 * invw, 0.f);
            *(float4*)&p.out[(size_t)d * 64 + 4 * l] = o;
        }
    }
}

// ---------------------------------------------------------------------------
// Fallback pipeline (round-6 verified kernels), used if coop launch fails.
// ---------------------------------------------------------------------------
__global__ __launch_bounds__(256) void bin_prep(
    const int* __restrict__ src, const int* __restrict__ dst,
    int* __restrict__ gcur, unsigned* __restrict__ binned, int E, int K,
    const float* __restrict__ W1s, const float* __restrict__ a1s,
    const float* __restrict__ W1d, const float* __restrict__ a1d,
    const float* __restrict__ W2s, const float* __restrict__ a2s,
    const float* __restrict__ W2d, const float* __restrict__ a2d,
    const float* __restrict__ Wl1, const float* __restrict__ Wl2,
    __half* __restrict__ wf) {
    int t = threadIdx.x;
    if (blockIdx.x == gridDim.x - 1) {
        __shared__ float vsm[256];
        {
            int g = t >> 6, k = t & 63;
            const float* W = (g == 0) ? W1s : (g == 1) ? W1d : (g == 2) ? W2s : W2d;
            const float* a = (g == 0) ? a1s : (g == 1) ? a1d : (g == 2) ? a2s : a2d;
            float s = 0.f;
            #pragma unroll 8
            for (int j = 0; j < 64; ++j) s += W[k * 64 + j] * a[j];
            vsm[t] = s;
        }
        __syncthreads();
        __half* wS1 = wf;
        __half* wL1 = wf + 4096;
        __half* wV1 = wf + 8192;
        __half* wS2 = wf + 9216;
        __half* wL2 = wf + 13312;
        __half* wV2 = wf + 17408;
        for (int e = t; e < 4096; e += 256) {
            int j = e & 7, ln = (e >> 3) & 63, tile = e >> 9;
            int nt = tile >> 1, kt = tile & 1;
            int kk = kt * 32 + ((ln >> 4) << 3) + j;
            int nn = (nt << 4) + (ln & 15);
            int wi = kk * 64 + nn;
            wS1[e] = __float2half(W1s[wi]);
            wL1[e] = __float2half(Wl1[wi]);
            wS2[e] = __float2half(W2s[wi]);
            wL2[e] = __float2half(Wl2[wi]);
        }
        for (int e = t; e < 1024; e += 256) {
            int j = e & 7, ln = (e >> 3) & 63, kt = e >> 9;
            int kk = kt * 32 + ((ln >> 4) << 3) + j;
            int nn = ln & 15;
            float v1 = (nn == 0) ? vsm[kk] : (nn == 1) ? vsm[64 + kk] : 0.f;
            float v2 = (nn == 0) ? vsm[128 + kk] : (nn == 1) ? vsm[192 + kk] : 0.f;
            wV1[e] = __float2half(v1);
            wV2[e] = __float2half(v2);
        }
        return;
    }
    __shared__ int h[128], cbase[128], cur[128];
    if (t < 128) h[t] = 0;
    __syncthreads();
    int base = blockIdx.x * 2048;
    #pragma unroll
    for (int i = 0; i < 8; ++i) {
        int idx = base + i * 256 + t;
        if (idx < E) atomicAdd(&h[dst[idx] >> BSHIFT], 1);
    }
    __syncthreads();
    if (t < K) {
        cbase[t] = t * ECAP + (h[t] ? atomicAdd(&gcur[t], h[t]) : 0);
        cur[t] = 0;
    }
    __syncthreads();
    #pragma unroll
    for (int i = 0; i < 8; ++i) {
        int idx = base + i * 256 + t;
        if (idx < E) {
            int d = dst[idx], s = src[idx];
            int b = d >> BSHIFT;
            int pos = cbase[b] + atomicAdd(&cur[b], 1);
            binned[pos] = ((unsigned)s << BSHIFT) | (unsigned)(d & (BNODES - 1));
        }
    }
}

__global__ __launch_bounds__(256) void csr_gemm(
    const unsigned* __restrict__ binned, int* __restrict__ ssrc,
    const int* __restrict__ gcur, int* __restrict__ rowbeg, int* __restrict__ rowend,
    const float* __restrict__ x, const __half* __restrict__ wsF,
    const __half* __restrict__ wlF, const __half* __restrict__ wvF,
    const float* __restrict__ bconv, const float* __restrict__ blin,
    unsigned* __restrict__ hsrc8, float* __restrict__ base_out,
    float* __restrict__ asrc, float* __restrict__ adst, int N, int K) {
    __shared__ union {
        struct { int lh[512]; int ps[256]; } c;
        _Float16 xh[64 * 72];
        float    xf[64 * 68];
    } sm;
    int tid = threadIdx.x;
    int blk = blockIdx.x;

    if (blk < K) {
        int base = blk * ECAP;
        int cnt = min(gcur[blk], ECAP);
        sm.c.lh[tid] = 0; sm.c.lh[tid + 256] = 0;
        __syncthreads();
        for (int i = tid; i < cnt; i += 256)
            atomicAdd(&sm.c.lh[binned[base + i] & (BNODES - 1)], 1);
        __syncthreads();
        int a0 = sm.c.lh[2 * tid], a1 = sm.c.lh[2 * tid + 1];
        sm.c.ps[tid] = a0 + a1;
        __syncthreads();
        for (int off = 1; off < 256; off <<= 1) {
            int v = (tid >= off) ? sm.c.ps[tid - off] : 0;
            __syncthreads();
            sm.c.ps[tid] += v;
            __syncthreads();
        }
        int exc = sm.c.ps[tid] - (a0 + a1);
        int node0 = blk * BNODES + 2 * tid, node1 = node0 + 1;
        if (node0 < N) { rowbeg[node0] = base + exc;      rowend[node0] = base + exc + a0; }
        if (node1 < N) { rowbeg[node1] = base + exc + a0; rowend[node1] = base + exc + a0 + a1; }
        __syncthreads();
        sm.c.lh[2 * tid] = exc; sm.c.lh[2 * tid + 1] = exc + a0;
        __syncthreads();
        for (int i = tid; i < cnt; i += 256) {
            unsigned e = binned[base + i];
            int pos = atomicAdd(&sm.c.lh[e & (BNODES - 1)], 1);
            ssrc[base + pos] = (int)(e >> BSHIFT);
        }
        return;
    }

    int gb = blk - K;
    int row0 = gb * 64;
    int rows = min(64, N - row0);
    #pragma unroll
    for (int i = 0; i < 4; ++i) {
        int u = tid + i * 256;
        int r = u >> 4, c4 = (u & 15) * 4;
        if (r < rows) {
            float4 v = *(const float4*)&x[(size_t)(row0 + r) * 64 + c4];
            *(__half2*)&sm.xh[r * 72 + c4]     = __floats2half2_rn(v.x, v.y);
            *(__half2*)&sm.xh[r * 72 + c4 + 2] = __floats2half2_rn(v.z, v.w);
        }
    }
    __syncthreads();
    mfma_tile(tid, row0, rows, sm.xh, sm.xf, wsF, wlF, wvF,
              bconv, blin, hsrc8, base_out, asrc, adst);
}

__global__ __launch_bounds__(256) void agg_gemm2(
    const int* __restrict__ rowbeg, const int* __restrict__ rowend,
    const int* __restrict__ ssrc,
    const float* __restrict__ asrc1, const float* __restrict__ adst1,
    const unsigned* __restrict__ h4_1, const float* __restrict__ base1,
    const __half* __restrict__ wsF, const __half* __restrict__ wlF,
    const __half* __restrict__ wvF,
    const float* __restrict__ bconv, const float* __restrict__ blin,
    unsigned* __restrict__ hsrc8_2, float* __restrict__ base2,
    float* __restrict__ asrc2, float* __restrict__ adst2, int N) {
    __shared__ union {
        _Float16 xh[64 * 72];
        float    xf[64 * 68];
    } sm;
    int tid = threadIdx.x;
    int row0 = blockIdx.x * 64;
    int rows = min(64, N - row0);
    int g = tid >> 4, l = tid & 15;
    #pragma unroll
    for (int r = 0; r < 4; ++r) {
        int rl = r * 16 + g;
        int d = row0 + rl;
        if (rl < rows) {
            float a0, a1, a2, a3, sw;
            agg16(rowbeg[d], rowend[d], adst1[d], l, ssrc, asrc1, h4_1,
                  a0, a1, a2, a3, sw);
            float4 b4 = *(const float4*)&base1[(size_t)d * 64 + 4 * l];
            float invw = (sw > 0.f) ? 1.f / sw : 0.f;
            __half2 p0 = __floats2half2_rn(fmaxf(b4.x + a0 * invw, 0.f),
                                           fmaxf(b4.y + a1 * invw, 0.f));
            __half2 p1 = __floats2half2_rn(fmaxf(b4.z + a2 * invw, 0.f),
                                           fmaxf(b4.w + a3 * invw, 0.f));
            *(__half2*)&sm.xh[rl * 72 + 4 * l]     = p0;
            *(__half2*)&sm.xh[rl * 72 + 4 * l + 2] = p1;
        }
    }
    __syncthreads();
    mfma_tile(tid, row0, rows, sm.xh, sm.xf, wsF, wlF, wvF,
              bconv, blin, hsrc8_2, base2, asrc2, adst2);
}

__global__ __launch_bounds__(256) void gat_aggregate_f(
    const int* __restrict__ rowbeg, const int* __restrict__ rowend,
    const int* __restrict__ ssrc,
    const float* __restrict__ asrc, const float* __restrict__ adst,
    const unsigned* __restrict__ h4, const float* __restrict__ base,
    float* __restrict__ out, int N) {
    int d = blockIdx.x * 16 + (threadIdx.x >> 4);
    int l = threadIdx.x & 15;
    if (d >= N) return;
    float a0, a1, a2, a3, sw;
    agg16(rowbeg[d], rowend[d], adst[d], l, ssrc, asrc, h4,
          a0, a1, a2, a3, sw);
    float4 b4 = *(const float4*)&base[(size_t)d * 64 + 4 * l];
    float invw = (sw > 0.f) ? 1.f / sw : 0.f;
    float4 o;
    o.x = fmaxf(b4.x + a0 * invw, 0.f);
    o.y = fmaxf(b4.y + a1 * invw, 0.f);
    o.z = fmaxf(b4.z + a2 * invw, 0.f);
    o.w = fmaxf(b4.w + a3 * invw, 0.f);
    *(float4*)&out[(size_t)d * 64 + 4 * l] = o;
}

// ---------------------------------------------------------------------------
extern "C" void kernel_launch(void* const* d_in, const int* in_sizes, int n_in,
                              void* d_out, int out_size, void* d_ws, size_t ws_size,
                              hipStream_t stream) {
    const float* x    = (const float*)d_in[0];
    const int*   ei   = (const int*)d_in[1];

    const int N = in_sizes[0] / 64;          // 50000
    const int E = in_sizes[1] / 2;           // 1200000
    const int K = (N + BNODES - 1) >> BSHIFT;  // 98 buckets

    float* ws = (float*)d_ws;
    size_t o = 0;
    unsigned* hsrc8_1 = (unsigned*)(ws + o); o += (size_t)N * 16;
    unsigned* hsrc8_2 = (unsigned*)(ws + o); o += (size_t)N * 16;
    float* base1  = ws + o; o += (size_t)N * 64;
    float* base2  = ws + o; o += (size_t)N * 64;
    float* asrc1  = ws + o; o += N;
    float* adst1  = ws + o; o += N;
    float* asrc2  = ws + o; o += N;
    float* adst2  = ws + o; o += N;
    __half* wf    = (__half*)(ws + o); o += 9216;
    int* rowbeg = (int*)(ws + o); o += N;
    int* rowend = (int*)(ws + o); o += N;
    int* gcur   = (int*)(ws + o); o += 128;
    unsigned* binned = (unsigned*)(ws + o); o += (size_t)K * ECAP;
    int* ssrc   = (int*)(ws + o); o += (size_t)K * ECAP;

    MegaP p;
    p.src = ei; p.dst = ei + E;
    p.gcur = gcur; p.binned = binned;
    p.E = E; p.K = K; p.N = N;
    p.EB = (E + 2047) / 2048;
    p.GB = (N + 63) / 64;
    p.AB = (N + 15) / 16;
    p.W1s = (const float*)d_in[2];  p.a1s = (const float*)d_in[4];
    p.W1d = (const float*)d_in[3];  p.a1d = (const float*)d_in[5];
    p.W2s = (const float*)d_in[9];  p.a2s = (const float*)d_in[11];
    p.W2d = (const float*)d_in[10]; p.a2d = (const float*)d_in[12];
    p.Wl1 = (const float*)d_in[7];  p.Wl2 = (const float*)d_in[14];
    p.wf = wf;
    p.ssrc = ssrc; p.rowbeg = rowbeg; p.rowend = rowend;
    p.x = x;
    p.b1 = (const float*)d_in[6];  p.bl1 = (const float*)d_in[8];
    p.b2 = (const float*)d_in[13]; p.bl2 = (const float*)d_in[15];
    p.hsrc8_1 = hsrc8_1; p.base1 = base1; p.asrc1 = asrc1; p.adst1 = adst1;
    p.hsrc8_2 = hsrc8_2; p.base2 = base2; p.asrc2 = asrc2; p.adst2 = adst2;
    p.out = (float*)d_out;

    // Cooperative grid sized by the runtime's own occupancy answer (cached).
    static int coop_grid = -2;
    if (coop_grid == -2) {
        int maxb = 0;
        hipError_t oe = hipOccupancyMaxActiveBlocksPerMultiprocessor(
            &maxb, reinterpret_cast<const void*>(&mega), 256, 0);
        if (oe == hipSuccess && maxb > 0) {
            long g = (long)maxb * 256;          // 256 CUs on MI355X
            if (g > 1024) g = 1024;
            coop_grid = (int)g;
        } else {
            coop_grid = -1;
        }
    }

    bool done = false;
    if (coop_grid > 0) {
        void* kargs[] = { (void*)&p };
        hipError_t e = hipLaunchCooperativeKernel(
            reinterpret_cast<const void*>(&mega),
            dim3(coop_grid), dim3(256), kargs, 0, stream);
        done = (e == hipSuccess);
    }

    if (!done) {
        const __half* wS1 = wf;
        const __half* wL1 = wf + 4096;
        const __half* wV1 = wf + 8192;
        const __half* wS2 = wf + 9216;
        const __half* wL2 = wf + 13312;
        const __half* wV2 = wf + 17408;
        const int* src = ei;
        const int* dst = ei + E;
        const int EB = (E + 2047) / 2048;
        const int GB = (N + 63) / 64;
        const int AB = (N + 15) / 16;

        (void)hipMemsetAsync(gcur, 0, 128 * sizeof(int), stream);
        bin_prep<<<EB + 1, 256, 0, stream>>>(src, dst, gcur, binned, E, K,
                                             p.W1s, p.a1s, p.W1d, p.a1d,
                                             p.W2s, p.a2s, p.W2d, p.a2d,
                                             p.Wl1, p.Wl2, wf);
        csr_gemm<<<K + GB, 256, 0, stream>>>(
            binned, ssrc, gcur, rowbeg, rowend,
            x, wS1, wL1, wV1, p.b1, p.bl1,
            hsrc8_1, base1, asrc1, adst1, N, K);
        agg_gemm2<<<GB, 256, 0, stream>>>(
            rowbeg, rowend, ssrc, asrc1, adst1, hsrc8_1, base1,
            wS2, wL2, wV2, p.b2, p.bl2,
            hsrc8_2, base2, asrc2, adst2, N);
        gat_aggregate_f<<<AB, 256, 0, stream>>>(
            rowbeg, rowend, ssrc, asrc2, adst2, hsrc8_2, base2,
            (float*)d_out, N);
    }
}

// Round 9
// 203.065 us; speedup vs baseline: 4.1566x; 4.1566x over previous
//
#include <hip/hip_runtime.h>
#include <hip/hip_fp16.h>

#define NEG 0.2f
#define BSHIFT 9
#define BNODES 512          // dst nodes per bucket
#define ECAP 14336          // fixed region per bucket (mean ~12288, sd ~110 -> +18 sigma)

typedef _Float16 half8_t __attribute__((ext_vector_type(8)));
typedef float   floatx4_t __attribute__((ext_vector_type(4)));
typedef float   floatx2_t __attribute__((ext_vector_type(2)));

// ---------------------------------------------------------------------------
// Aggregation core: one dst node per 16-lane group (4 nodes/wave).
// Lane l owns channels 4l..4l+3. No shuffles, no reduction (sumw replicated).
// 8-edge ILP: 8 ssrc loads issue together, then 16 independent gathers
// (8 asrc + 8 h4) in flight -> halves exposed latency steps vs 4-wide.
// ---------------------------------------------------------------------------
__device__ __forceinline__ void agg16(
    int beg, int end, float ad, int l,
    const int* __restrict__ ssrc, const float* __restrict__ asrc,
    const unsigned* __restrict__ h4,
    float& a0, float& a1, float& a2, float& a3, float& sumw) {
    a0 = a1 = a2 = a3 = sumw = 0.f;
    int e = beg;
    for (; e + 7 < end; e += 8) {
        int s0 = ssrc[e],     s1 = ssrc[e + 1], s2 = ssrc[e + 2], s3 = ssrc[e + 3];
        int s4 = ssrc[e + 4], s5 = ssrc[e + 5], s6 = ssrc[e + 6], s7 = ssrc[e + 7];
        float x0 = asrc[s0] + ad, x1 = asrc[s1] + ad;
        float x2 = asrc[s2] + ad, x3 = asrc[s3] + ad;
        float x4 = asrc[s4] + ad, x5 = asrc[s5] + ad;
        float x6 = asrc[s6] + ad, x7 = asrc[s7] + ad;
        unsigned v0 = h4[(size_t)s0 * 16 + l];
        unsigned v1 = h4[(size_t)s1 * 16 + l];
        unsigned v2 = h4[(size_t)s2 * 16 + l];
        unsigned v3 = h4[(size_t)s3 * 16 + l];
        unsigned v4 = h4[(size_t)s4 * 16 + l];
        unsigned v5 = h4[(size_t)s5 * 16 + l];
        unsigned v6 = h4[(size_t)s6 * 16 + l];
        unsigned v7 = h4[(size_t)s7 * 16 + l];
        x0 = (x0 >= 0.f) ? x0 : NEG * x0;
        x1 = (x1 >= 0.f) ? x1 : NEG * x1;
        x2 = (x2 >= 0.f) ? x2 : NEG * x2;
        x3 = (x3 >= 0.f) ? x3 : NEG * x3;
        x4 = (x4 >= 0.f) ? x4 : NEG * x4;
        x5 = (x5 >= 0.f) ? x5 : NEG * x5;
        x6 = (x6 >= 0.f) ? x6 : NEG * x6;
        x7 = (x7 >= 0.f) ? x7 : NEG * x7;
        float w0 = __expf(x0), w1 = __expf(x1), w2 = __expf(x2), w3 = __expf(x3);
        float w4 = __expf(x4), w5 = __expf(x5), w6 = __expf(x6), w7 = __expf(x7);
        floatx2_t f00 = __builtin_amdgcn_cvt_pk_f32_fp8(v0, false);
        floatx2_t f01 = __builtin_amdgcn_cvt_pk_f32_fp8(v0, true);
        floatx2_t f10 = __builtin_amdgcn_cvt_pk_f32_fp8(v1, false);
        floatx2_t f11 = __builtin_amdgcn_cvt_pk_f32_fp8(v1, true);
        floatx2_t f20 = __builtin_amdgcn_cvt_pk_f32_fp8(v2, false);
        floatx2_t f21 = __builtin_amdgcn_cvt_pk_f32_fp8(v2, true);
        floatx2_t f30 = __builtin_amdgcn_cvt_pk_f32_fp8(v3, false);
        floatx2_t f31 = __builtin_amdgcn_cvt_pk_f32_fp8(v3, true);
        floatx2_t f40 = __builtin_amdgcn_cvt_pk_f32_fp8(v4, false);
        floatx2_t f41 = __builtin_amdgcn_cvt_pk_f32_fp8(v4, true);
        floatx2_t f50 = __builtin_amdgcn_cvt_pk_f32_fp8(v5, false);
        floatx2_t f51 = __builtin_amdgcn_cvt_pk_f32_fp8(v5, true);
        floatx2_t f60 = __builtin_amdgcn_cvt_pk_f32_fp8(v6, false);
        floatx2_t f61 = __builtin_amdgcn_cvt_pk_f32_fp8(v6, true);
        floatx2_t f70 = __builtin_amdgcn_cvt_pk_f32_fp8(v7, false);
        floatx2_t f71 = __builtin_amdgcn_cvt_pk_f32_fp8(v7, true);
        sumw += ((w0 + w1) + (w2 + w3)) + ((w4 + w5) + (w6 + w7));
        a0 += (w0 * f00.x + w1 * f10.x + w2 * f20.x + w3 * f30.x)
            + (w4 * f40.x + w5 * f50.x + w6 * f60.x + w7 * f70.x);
        a1 += (w0 * f00.y + w1 * f10.y + w2 * f20.y + w3 * f30.y)
            + (w4 * f40.y + w5 * f50.y + w6 * f60.y + w7 * f70.y);
        a2 += (w0 * f01.x + w1 * f11.x + w2 * f21.x + w3 * f31.x)
            + (w4 * f41.x + w5 * f51.x + w6 * f61.x + w7 * f71.x);
        a3 += (w0 * f01.y + w1 * f11.y + w2 * f21.y + w3 * f31.y)
            + (w4 * f41.y + w5 * f51.y + w6 * f61.y + w7 * f71.y);
    }
    for (; e + 3 < end; e += 4) {
        int s0 = ssrc[e], s1 = ssrc[e + 1], s2 = ssrc[e + 2], s3 = ssrc[e + 3];
        float x0 = asrc[s0] + ad, x1 = asrc[s1] + ad;
        float x2 = asrc[s2] + ad, x3 = asrc[s3] + ad;
        unsigned v0 = h4[(size_t)s0 * 16 + l];
        unsigned v1 = h4[(size_t)s1 * 16 + l];
        unsigned v2 = h4[(size_t)s2 * 16 + l];
        unsigned v3 = h4[(size_t)s3 * 16 + l];
        x0 = (x0 >= 0.f) ? x0 : NEG * x0;
        x1 = (x1 >= 0.f) ? x1 : NEG * x1;
        x2 = (x2 >= 0.f) ? x2 : NEG * x2;
        x3 = (x3 >= 0.f) ? x3 : NEG * x3;
        float w0 = __expf(x0), w1 = __expf(x1), w2 = __expf(x2), w3 = __expf(x3);
        floatx2_t f00 = __builtin_amdgcn_cvt_pk_f32_fp8(v0, false);
        floatx2_t f01 = __builtin_amdgcn_cvt_pk_f32_fp8(v0, true);
        floatx2_t f10 = __builtin_amdgcn_cvt_pk_f32_fp8(v1, false);
        floatx2_t f11 = __builtin_amdgcn_cvt_pk_f32_fp8(v1, true);
        floatx2_t f20 = __builtin_amdgcn_cvt_pk_f32_fp8(v2, false);
        floatx2_t f21 = __builtin_amdgcn_cvt_pk_f32_fp8(v2, true);
        floatx2_t f30 = __builtin_amdgcn_cvt_pk_f32_fp8(v3, false);
        floatx2_t f31 = __builtin_amdgcn_cvt_pk_f32_fp8(v3, true);
        sumw += (w0 + w1) + (w2 + w3);
        a0 += w0 * f00.x + w1 * f10.x + w2 * f20.x + w3 * f30.x;
        a1 += w0 * f00.y + w1 * f10.y + w2 * f20.y + w3 * f30.y;
        a2 += w0 * f01.x + w1 * f11.x + w2 * f21.x + w3 * f31.x;
        a3 += w0 * f01.y + w1 * f11.y + w2 * f21.y + w3 * f31.y;
    }
    for (; e < end; ++e) {
        int s = ssrc[e];
        float x = asrc[s] + ad;
        unsigned v = h4[(size_t)s * 16 + l];
        x = (x >= 0.f) ? x : NEG * x;
        float w = __expf(x);
        floatx2_t f0 = __builtin_amdgcn_cvt_pk_f32_fp8(v, false);
        floatx2_t f1 = __builtin_amdgcn_cvt_pk_f32_fp8(v, true);
        sumw += w;
        a0 += w * f0.x; a1 += w * f0.y;
        a2 += w * f1.x; a3 += w * f1.y;
    }
}

// ---------------------------------------------------------------------------
// K1: blockIdx < EB -> bin edges into fixed bucket regions; last block ->
// build MFMA B-fragment-ordered fp16 weights + folded attention columns.
// ---------------------------------------------------------------------------
__global__ __launch_bounds__(256) void bin_prep(
    const int* __restrict__ src, const int* __restrict__ dst,
    int* __restrict__ gcur, unsigned* __restrict__ binned, int E, int K,
    const float* __restrict__ W1s, const float* __restrict__ a1s,
    const float* __restrict__ W1d, const float* __restrict__ a1d,
    const float* __restrict__ W2s, const float* __restrict__ a2s,
    const float* __restrict__ W2d, const float* __restrict__ a2d,
    const float* __restrict__ Wl1, const float* __restrict__ Wl2,
    __half* __restrict__ wf) {
    int t = threadIdx.x;
    if (blockIdx.x == gridDim.x - 1) {
        __shared__ float vsm[256];
        {
            int g = t >> 6, k = t & 63;
            const float* W = (g == 0) ? W1s : (g == 1) ? W1d : (g == 2) ? W2s : W2d;
            const float* a = (g == 0) ? a1s : (g == 1) ? a1d : (g == 2) ? a2s : a2d;
            float s = 0.f;
            #pragma unroll 8
            for (int j = 0; j < 64; ++j) s += W[k * 64 + j] * a[j];
            vsm[t] = s;
        }
        __syncthreads();
        __half* wS1 = wf;
        __half* wL1 = wf + 4096;
        __half* wV1 = wf + 8192;
        __half* wS2 = wf + 9216;
        __half* wL2 = wf + 13312;
        __half* wV2 = wf + 17408;
        for (int e = t; e < 4096; e += 256) {
            int j = e & 7, ln = (e >> 3) & 63, tile = e >> 9;
            int nt = tile >> 1, kt = tile & 1;
            int kk = kt * 32 + ((ln >> 4) << 3) + j;
            int nn = (nt << 4) + (ln & 15);
            int wi = kk * 64 + nn;
            wS1[e] = __float2half(W1s[wi]);
            wL1[e] = __float2half(Wl1[wi]);
            wS2[e] = __float2half(W2s[wi]);
            wL2[e] = __float2half(Wl2[wi]);
        }
        for (int e = t; e < 1024; e += 256) {
            int j = e & 7, ln = (e >> 3) & 63, kt = e >> 9;
            int kk = kt * 32 + ((ln >> 4) << 3) + j;
            int nn = ln & 15;
            float v1 = (nn == 0) ? vsm[kk] : (nn == 1) ? vsm[64 + kk] : 0.f;
            float v2 = (nn == 0) ? vsm[128 + kk] : (nn == 1) ? vsm[192 + kk] : 0.f;
            wV1[e] = __float2half(v1);
            wV2[e] = __float2half(v2);
        }
        return;
    }
    __shared__ int h[128], cbase[128], cur[128];
    if (t < 128) h[t] = 0;
    __syncthreads();
    int base = blockIdx.x * 2048;
    #pragma unroll
    for (int i = 0; i < 8; ++i) {
        int idx = base + i * 256 + t;
        if (idx < E) atomicAdd(&h[dst[idx] >> BSHIFT], 1);
    }
    __syncthreads();
    if (t < K) {
        cbase[t] = t * ECAP + (h[t] ? atomicAdd(&gcur[t], h[t]) : 0);
        cur[t] = 0;
    }
    __syncthreads();
    #pragma unroll
    for (int i = 0; i < 8; ++i) {
        int idx = base + i * 256 + t;
        if (idx < E) {
            int d = dst[idx], s = src[idx];
            int b = d >> BSHIFT;
            int pos = cbase[b] + atomicAdd(&cur[b], 1);
            binned[pos] = ((unsigned)s << BSHIFT) | (unsigned)(d & (BNODES - 1));
        }
    }
}

// ---------------------------------------------------------------------------
// MFMA GEMM tile: 64 rows fp16 in xh[64][72]. Wave w owns rows 16w..16w+15.
// 18 MFMAs; epilogue LDS-bounces: hsrc -> fp8 (packed), base -> fp32 (+bias),
// asrc/adst from the attention MFMA's C-frag columns 0/1.
// ---------------------------------------------------------------------------
__device__ __forceinline__ void mfma_tile(
    int tid, int row0, int rows,
    _Float16* xh, float* xf,            // aliased LDS (union), used sequentially
    const __half* wsF, const __half* wlF, const __half* wvF,
    const float* __restrict__ bconv, const float* __restrict__ blin,
    unsigned* __restrict__ hsrc8, float* __restrict__ base_out,
    float* __restrict__ asrc, float* __restrict__ adst) {
    int w = tid >> 6, lane = tid & 63, m = lane & 15, q = lane >> 4;
    half8_t a0 = *(const half8_t*)&xh[(w * 16 + m) * 72 + q * 8];
    half8_t a1 = *(const half8_t*)&xh[(w * 16 + m) * 72 + 32 + q * 8];
    const half8_t* bS = (const half8_t*)(const void*)wsF;
    const half8_t* bL = (const half8_t*)(const void*)wlF;
    const half8_t* bV = (const half8_t*)(const void*)wvF;
    floatx4_t z = {0.f, 0.f, 0.f, 0.f};
    floatx4_t cs[4], cl[4], cv;
    #pragma unroll
    for (int nt = 0; nt < 4; ++nt) {
        cs[nt] = __builtin_amdgcn_mfma_f32_16x16x32_f16(a0, bS[(nt * 2 + 0) * 64 + lane], z, 0, 0, 0);
        cs[nt] = __builtin_amdgcn_mfma_f32_16x16x32_f16(a1, bS[(nt * 2 + 1) * 64 + lane], cs[nt], 0, 0, 0);
        cl[nt] = __builtin_amdgcn_mfma_f32_16x16x32_f16(a0, bL[(nt * 2 + 0) * 64 + lane], z, 0, 0, 0);
        cl[nt] = __builtin_amdgcn_mfma_f32_16x16x32_f16(a1, bL[(nt * 2 + 1) * 64 + lane], cl[nt], 0, 0, 0);
    }
    cv = __builtin_amdgcn_mfma_f32_16x16x32_f16(a0, bV[lane], z, 0, 0, 0);
    cv = __builtin_amdgcn_mfma_f32_16x16x32_f16(a1, bV[64 + lane], cv, 0, 0, 0);
    __syncthreads();
    #pragma unroll
    for (int nt = 0; nt < 4; ++nt)
        #pragma unroll
        for (int r = 0; r < 4; ++r)
            xf[(w * 16 + q * 4 + r) * 68 + nt * 16 + m] = cs[nt][r];
    __syncthreads();
    #pragma unroll
    for (int i = 0; i < 2; ++i) {
        int u = tid + i * 256;
        int r = u >> 3, c8 = (u & 7) * 8;
        if (r < rows) {
            float4 v0 = *(const float4*)&xf[r * 68 + c8];
            float4 v1 = *(const float4*)&xf[r * 68 + c8 + 4];
            int lo = __builtin_amdgcn_cvt_pk_fp8_f32(v0.x, v0.y, 0, false);
            lo = __builtin_amdgcn_cvt_pk_fp8_f32(v0.z, v0.w, lo, true);
            int hi = __builtin_amdgcn_cvt_pk_fp8_f32(v1.x, v1.y, 0, false);
            hi = __builtin_amdgcn_cvt_pk_fp8_f32(v1.z, v1.w, hi, true);
            uint2 pk; pk.x = (unsigned)lo; pk.y = (unsigned)hi;
            *(uint2*)&hsrc8[(size_t)(row0 + r) * 16 + (u & 7) * 2] = pk;
        }
    }
    __syncthreads();
    float bb[4];
    bb[0] = bconv[m] + blin[m];
    bb[1] = bconv[16 + m] + blin[16 + m];
    bb[2] = bconv[32 + m] + blin[32 + m];
    bb[3] = bconv[48 + m] + blin[48 + m];
    #pragma unroll
    for (int nt = 0; nt < 4; ++nt)
        #pragma unroll
        for (int r = 0; r < 4; ++r)
            xf[(w * 16 + q * 4 + r) * 68 + nt * 16 + m] = cl[nt][r] + bb[nt];
    __syncthreads();
    #pragma unroll
    for (int i = 0; i < 4; ++i) {
        int u = tid + i * 256;
        int r = u >> 4, c4 = (u & 15) * 4;
        if (r < rows)
            *(float4*)&base_out[(size_t)(row0 + r) * 64 + c4] = *(const float4*)&xf[r * 68 + c4];
    }
    int rb = w * 16 + q * 4;
    if (m == 0) {
        #pragma unroll
        for (int r = 0; r < 4; ++r)
            if (rb + r < rows) asrc[row0 + rb + r] = cv[r];
    } else if (m == 1) {
        #pragma unroll
        for (int r = 0; r < 4; ++r)
            if (rb + r < rows) adst[row0 + rb + r] = cv[r];
    }
}

// ---------------------------------------------------------------------------
// K2: blockIdx < K -> per-bucket CSR finalize; else conv1 MFMA gemm tile.
// ---------------------------------------------------------------------------
__global__ __launch_bounds__(256) void csr_gemm(
    const unsigned* __restrict__ binned, int* __restrict__ ssrc,
    const int* __restrict__ gcur, int* __restrict__ rowbeg, int* __restrict__ rowend,
    const float* __restrict__ x, const __half* __restrict__ wsF,
    const __half* __restrict__ wlF, const __half* __restrict__ wvF,
    const float* __restrict__ bconv, const float* __restrict__ blin,
    unsigned* __restrict__ hsrc8, float* __restrict__ base_out,
    float* __restrict__ asrc, float* __restrict__ adst, int N, int K) {
    __shared__ union {
        struct { int lh[512]; int ps[256]; } c;
        _Float16 xh[64 * 72];
        float    xf[64 * 68];
    } sm;
    int tid = threadIdx.x;
    int blk = blockIdx.x;

    if (blk < K) {
        int base = blk * ECAP;
        int cnt = min(gcur[blk], ECAP);
        sm.c.lh[tid] = 0; sm.c.lh[tid + 256] = 0;
        __syncthreads();
        for (int i = tid; i < cnt; i += 256)
            atomicAdd(&sm.c.lh[binned[base + i] & (BNODES - 1)], 1);
        __syncthreads();
        int a0 = sm.c.lh[2 * tid], a1 = sm.c.lh[2 * tid + 1];
        sm.c.ps[tid] = a0 + a1;
        __syncthreads();
        for (int off = 1; off < 256; off <<= 1) {
            int v = (tid >= off) ? sm.c.ps[tid - off] : 0;
            __syncthreads();
            sm.c.ps[tid] += v;
            __syncthreads();
        }
        int exc = sm.c.ps[tid] - (a0 + a1);
        int node0 = blk * BNODES + 2 * tid, node1 = node0 + 1;
        if (node0 < N) { rowbeg[node0] = base + exc;      rowend[node0] = base + exc + a0; }
        if (node1 < N) { rowbeg[node1] = base + exc + a0; rowend[node1] = base + exc + a0 + a1; }
        __syncthreads();
        sm.c.lh[2 * tid] = exc; sm.c.lh[2 * tid + 1] = exc + a0;
        __syncthreads();
        for (int i = tid; i < cnt; i += 256) {
            unsigned e = binned[base + i];
            int pos = atomicAdd(&sm.c.lh[e & (BNODES - 1)], 1);
            ssrc[base + pos] = (int)(e >> BSHIFT);
        }
        return;
    }

    int gb = blk - K;
    int row0 = gb * 64;
    int rows = min(64, N - row0);
    #pragma unroll
    for (int i = 0; i < 4; ++i) {
        int u = tid + i * 256;
        int r = u >> 4, c4 = (u & 15) * 4;
        if (r < rows) {
            float4 v = *(const float4*)&x[(size_t)(row0 + r) * 64 + c4];
            *(__half2*)&sm.xh[r * 72 + c4]     = __floats2half2_rn(v.x, v.y);
            *(__half2*)&sm.xh[r * 72 + c4 + 2] = __floats2half2_rn(v.z, v.w);
        }
    }
    __syncthreads();
    mfma_tile(tid, row0, rows, sm.xh, sm.xf, wsF, wlF, wvF,
              bconv, blin, hsrc8, base_out, asrc, adst);
}

// ---------------------------------------------------------------------------
// K3 (fused): conv1 aggregate for 64 dst nodes straight into the LDS fp16
// tile (4 rounds x 16 node-groups), then conv2 MFMA gemm on that tile.
// Reads conv1 state (set 1), writes conv2 state (set 2).
// ---------------------------------------------------------------------------
__global__ __launch_bounds__(256) void agg_gemm2(
    const int* __restrict__ rowbeg, const int* __restrict__ rowend,
    const int* __restrict__ ssrc,
    const float* __restrict__ asrc1, const float* __restrict__ adst1,
    const unsigned* __restrict__ h4_1, const float* __restrict__ base1,
    const __half* __restrict__ wsF, const __half* __restrict__ wlF,
    const __half* __restrict__ wvF,
    const float* __restrict__ bconv, const float* __restrict__ blin,
    unsigned* __restrict__ hsrc8_2, float* __restrict__ base2,
    float* __restrict__ asrc2, float* __restrict__ adst2, int N) {
    __shared__ union {
        _Float16 xh[64 * 72];
        float    xf[64 * 68];
    } sm;
    int tid = threadIdx.x;
    int row0 = blockIdx.x * 64;
    int rows = min(64, N - row0);
    int g = tid >> 4, l = tid & 15;
    #pragma unroll
    for (int r = 0; r < 4; ++r) {
        int rl = r * 16 + g;
        int d = row0 + rl;
        if (rl < rows) {
            float a0, a1, a2, a3, sw;
            agg16(rowbeg[d], rowend[d], adst1[d], l, ssrc, asrc1, h4_1,
                  a0, a1, a2, a3, sw);
            float4 b4 = *(const float4*)&base1[(size_t)d * 64 + 4 * l];
            float invw = (sw > 0.f) ? 1.f / sw : 0.f;
            __half2 p0 = __floats2half2_rn(fmaxf(b4.x + a0 * invw, 0.f),
                                           fmaxf(b4.y + a1 * invw, 0.f));
            __half2 p1 = __floats2half2_rn(fmaxf(b4.z + a2 * invw, 0.f),
                                           fmaxf(b4.w + a3 * invw, 0.f));
            *(__half2*)&sm.xh[rl * 72 + 4 * l]     = p0;
            *(__half2*)&sm.xh[rl * 72 + 4 * l + 2] = p1;
        }
    }
    __syncthreads();
    mfma_tile(tid, row0, rows, sm.xh, sm.xf, wsF, wlF, wvF,
              bconv, blin, hsrc8_2, base2, asrc2, adst2);
}

// ---------------------------------------------------------------------------
// K4: conv2 aggregate -> fp32 output (reads set 2).
// ---------------------------------------------------------------------------
__global__ __launch_bounds__(256) void gat_aggregate_f(
    const int* __restrict__ rowbeg, const int* __restrict__ rowend,
    const int* __restrict__ ssrc,
    const float* __restrict__ asrc, const float* __restrict__ adst,
    const unsigned* __restrict__ h4, const float* __restrict__ base,
    float* __restrict__ out, int N) {
    int d = blockIdx.x * 16 + (threadIdx.x >> 4);
    int l = threadIdx.x & 15;
    if (d >= N) return;
    float a0, a1, a2, a3, sw;
    agg16(rowbeg[d], rowend[d], adst[d], l, ssrc, asrc, h4,
          a0, a1, a2, a3, sw);
    float4 b4 = *(const float4*)&base[(size_t)d * 64 + 4 * l];
    float invw = (sw > 0.f) ? 1.f / sw : 0.f;
    float4 o;
    o.x = fmaxf(b4.x + a0 * invw, 0.f);
    o.y = fmaxf(b4.y + a1 * invw, 0.f);
    o.z = fmaxf(b4.z + a2 * invw, 0.f);
    o.w = fmaxf(b4.w + a3 * invw, 0.f);
    *(float4*)&out[(size_t)d * 64 + 4 * l] = o;
}

// ---------------------------------------------------------------------------
extern "C" void kernel_launch(void* const* d_in, const int* in_sizes, int n_in,
                              void* d_out, int out_size, void* d_ws, size_t ws_size,
                              hipStream_t stream) {
    const float* x    = (const float*)d_in[0];
    const int*   ei   = (const int*)d_in[1];
    const float* W1s  = (const float*)d_in[2];
    const float* W1d  = (const float*)d_in[3];
    const float* a1s  = (const float*)d_in[4];
    const float* a1d  = (const float*)d_in[5];
    const float* b1   = (const float*)d_in[6];
    const float* Wl1  = (const float*)d_in[7];
    const float* bl1  = (const float*)d_in[8];
    const float* W2s  = (const float*)d_in[9];
    const float* W2d  = (const float*)d_in[10];
    const float* a2s  = (const float*)d_in[11];
    const float* a2d  = (const float*)d_in[12];
    const float* b2   = (const float*)d_in[13];
    const float* Wl2  = (const float*)d_in[14];
    const float* bl2  = (const float*)d_in[15];

    const int N = in_sizes[0] / 64;          // 50000
    const int E = in_sizes[1] / 2;           // 1200000
    const int* src = ei;
    const int* dst = ei + E;
    const int K = (N + BNODES - 1) >> BSHIFT;  // 98 buckets

    float* ws = (float*)d_ws;
    size_t o = 0;
    unsigned* hsrc8_1 = (unsigned*)(ws + o); o += (size_t)N * 16;  // fp8 [N][64] set1
    unsigned* hsrc8_2 = (unsigned*)(ws + o); o += (size_t)N * 16;  // fp8 [N][64] set2
    float* base1  = ws + o; o += (size_t)N * 64;
    float* base2  = ws + o; o += (size_t)N * 64;
    float* asrc1  = ws + o; o += N;
    float* adst1  = ws + o; o += N;
    float* asrc2  = ws + o; o += N;
    float* adst2  = ws + o; o += N;
    __half* wf    = (__half*)(ws + o); o += 9216;   // 18432 halfs of frag weights
    int* rowbeg = (int*)(ws + o); o += N;
    int* rowend = (int*)(ws + o); o += N;
    int* gcur   = (int*)(ws + o); o += 128;
    unsigned* binned = (unsigned*)(ws + o); o += (size_t)K * ECAP;
    int* ssrc   = (int*)(ws + o); o += (size_t)K * ECAP;

    const __half* wS1 = wf;
    const __half* wL1 = wf + 4096;
    const __half* wV1 = wf + 8192;
    const __half* wS2 = wf + 9216;
    const __half* wL2 = wf + 13312;
    const __half* wV2 = wf + 17408;

    const int EB = (E + 2047) / 2048;
    const int GB = (N + 63) / 64;
    const int AB = (N + 15) / 16;

    // ---- K1: bin_scatter (EB blocks) + weight-frag prep (1 block) ----
    (void)hipMemsetAsync(gcur, 0, 128 * sizeof(int), stream);
    bin_prep<<<EB + 1, 256, 0, stream>>>(src, dst, gcur, binned, E, K,
                                         W1s, a1s, W1d, a1d, W2s, a2s, W2d, a2d,
                                         Wl1, Wl2, wf);

    // ---- K2: local_csr (K blocks) + conv1 MFMA gemm (GB blocks) ----
    csr_gemm<<<K + GB, 256, 0, stream>>>(
        binned, ssrc, gcur, rowbeg, rowend,
        x, wS1, wL1, wV1, b1, bl1,
        hsrc8_1, base1, asrc1, adst1, N, K);

    // ---- K3: conv1 aggregate + conv2 MFMA gemm (fused) ----
    agg_gemm2<<<GB, 256, 0, stream>>>(
        rowbeg, rowend, ssrc, asrc1, adst1, hsrc8_1, base1,
        wS2, wL2, wV2, b2, bl2,
        hsrc8_2, base2, asrc2, adst2, N);

    // ---- K4: conv2 aggregate -> output ----
    gat_aggregate_f<<<AB, 256, 0, stream>>>(
        rowbeg, rowend, ssrc, asrc2, adst2, hsrc8_2, base2,
        (float*)d_out, N);
}